// Round 1
// baseline (1204.591 us; speedup 1.0000x reference)
//
#include <hip/hip_runtime.h>
#include <utility>

// SICE head for MI355X (gfx950).
// Pipeline: x --(k_xt: transpose+fp16)--> xt[b,hw,c]
//   k_conv: y = w@x per batch (fp16 MFMA, fp32 acc) + fused BN-stat atomics
//   k_bnfinal -> scale/shift ; k_bnapply -> yc fp16 (BN+relu+row-center)
//   k_gram: C = yc@yc^T/784 (fp16 MFMA)
//   NS chain (3 inv_sqrtm calls; SICE iter i=2 is a provable no-op):
//     all matrices symmetric -> C = A.rows dot B.rows (no transposes)
//     split-bf16 (hi+lo, 3 MFMA terms) for ~fp32 accuracy
//   k_sice elementwise updates (fp32), k_out triu-vec / sqrt(trace).
// Workspace: ~144 MB (NS buffers overlaid on dead xt region).

typedef unsigned short u16;
typedef __attribute__((ext_vector_type(8))) __bf16 bf16x8;
typedef __attribute__((ext_vector_type(8))) _Float16 f16x8;
typedef __attribute__((ext_vector_type(4))) float f32x4;

#define DEV __device__ __forceinline__

DEV u16 f2bf(float f) {
  unsigned x = __float_as_uint(f);
  x += 0x7fffu + ((x >> 16) & 1u);
  return (u16)(x >> 16);
}
DEV float bf2f(u16 h) { return __uint_as_float(((unsigned)h) << 16); }

// smallblk float-index layout
#define SB_SUM   0
#define SB_SSQ   256
#define SB_SCALE 512
#define SB_SHIFT 768
#define SB_IJ    1024
#define SB_TRC   1280
#define SB_TRX   1312
#define SB_TRL   1344

// ---------------- prep: w -> fp16, zero stats, ij vector ----------------
__global__ __launch_bounds__(256) void k_prep(const float* __restrict__ w,
                                              const float* __restrict__ jitter,
                                              _Float16* __restrict__ w_half,
                                              float* __restrict__ sb) {
  int gid = blockIdx.x * 256 + threadIdx.x;
  if (gid < 256 * 2048) w_half[gid] = (_Float16)w[gid];
  if (blockIdx.x == 0) {
    int t = threadIdx.x;
    sb[SB_SUM + t] = 0.f;
    sb[SB_SSQ + t] = 0.f;
    sb[SB_IJ + t] = 1e-10f + 1e-9f * jitter[t];
  }
}

// ---------------- x[b,c,hw] f32 -> xt[b,hw,c] f16 ----------------
__global__ __launch_bounds__(256) void k_xt(const float* __restrict__ x,
                                            _Float16* __restrict__ xt) {
  int ht = blockIdx.x;  // 0..12 (hw tiles of 64)
  int ct = blockIdx.y;  // 0..31 (c tiles of 64)
  int b = blockIdx.z;
  int t = threadIdx.x;
  __shared__ _Float16 ls[64 * 68];
  int hw0 = ht * 64, c0 = ct * 64;
  const float* xb = x + ((size_t)b * 2048 + c0) * 784;
#pragma unroll
  for (int it = 0; it < 4; ++it) {
    int cc = (t >> 4) + it * 16;
    int s = t & 15;
    int hw = hw0 + s * 4;
    float4 v = make_float4(0.f, 0.f, 0.f, 0.f);
    if (hw < 784) v = *(const float4*)(xb + (size_t)cc * 784 + hw);
    _Float16* d = &ls[cc * 68 + s * 4];
    d[0] = (_Float16)v.x; d[1] = (_Float16)v.y;
    d[2] = (_Float16)v.z; d[3] = (_Float16)v.w;
  }
  __syncthreads();
#pragma unroll
  for (int it = 0; it < 2; ++it) {
    int idx = t + it * 256;
    int hwr = idx >> 3, s8 = idx & 7;
    if (hw0 + hwr < 784) {
      union { _Float16 h[8]; uint4 v; } pk;
#pragma unroll
      for (int cc = 0; cc < 8; ++cc) pk.h[cc] = ls[(s8 * 8 + cc) * 68 + hwr];
      *(uint4*)(xt + ((size_t)b * 784 + hw0 + hwr) * 2048 + c0 + s8 * 8) = pk.v;
    }
  }
}

// ---------------- conv: y[b,d,hw] = sum_c w[d,c] x[b,c,hw] + BN stats -----
__global__ __launch_bounds__(256) void k_conv(const _Float16* __restrict__ w_half,
                                              const _Float16* __restrict__ xt,
                                              float* __restrict__ y,
                                              float* __restrict__ sb) {
  int ht = blockIdx.x;  // 0..12
  int b = blockIdx.y;
  int t = threadIdx.x;
  int wv = t >> 6, lane = t & 63, m = lane & 15, quad = lane >> 4;
  __shared__ _Float16 lsA[256 * 40];
  __shared__ _Float16 lsB[64 * 40];
  int hw0 = ht * 64;
  f32x4 acc[4][4];
#pragma unroll
  for (int i = 0; i < 4; ++i)
#pragma unroll
    for (int j = 0; j < 4; ++j) acc[i][j] = (f32x4){0.f, 0.f, 0.f, 0.f};
  int rowA = t >> 2, segA = t & 3;
  for (int kc = 0; kc < 64; ++kc) {
    int k0 = kc * 32;
#pragma unroll
    for (int rr = 0; rr < 4; ++rr) {
      int row = rowA + rr * 64;
      *(uint4*)&lsA[row * 40 + segA * 8] =
          *(const uint4*)(w_half + (size_t)row * 2048 + k0 + segA * 8);
    }
    {
      int hw = hw0 + rowA;
      uint4 v = {0u, 0u, 0u, 0u};
      if (hw < 784)
        v = *(const uint4*)(xt + ((size_t)b * 784 + hw) * 2048 + k0 + segA * 8);
      *(uint4*)&lsB[rowA * 40 + segA * 8] = v;
    }
    __syncthreads();
    f16x8 af[4], bfg[4];
#pragma unroll
    for (int i = 0; i < 4; ++i)
      af[i] = *(const f16x8*)&lsA[(wv * 64 + i * 16 + m) * 40 + quad * 8];
#pragma unroll
    for (int j = 0; j < 4; ++j)
      bfg[j] = *(const f16x8*)&lsB[(j * 16 + m) * 40 + quad * 8];
#pragma unroll
    for (int i = 0; i < 4; ++i)
#pragma unroll
      for (int j = 0; j < 4; ++j)
        acc[i][j] = __builtin_amdgcn_mfma_f32_16x16x32_f16(af[i], bfg[j], acc[i][j], 0, 0, 0);
    __syncthreads();
  }
  // BN stats: per-row sums across this WG's 64 hw cols
  float* sum = sb + SB_SUM;
  float* ssq = sb + SB_SSQ;
#pragma unroll
  for (int i = 0; i < 4; ++i) {
#pragma unroll
    for (int r = 0; r < 4; ++r) {
      float s = 0.f, q = 0.f;
#pragma unroll
      for (int j = 0; j < 4; ++j) {
        float v = acc[i][j][r];
        s += v; q += v * v;
      }
      s += __shfl_xor(s, 1); s += __shfl_xor(s, 2);
      s += __shfl_xor(s, 4); s += __shfl_xor(s, 8);
      q += __shfl_xor(q, 1); q += __shfl_xor(q, 2);
      q += __shfl_xor(q, 4); q += __shfl_xor(q, 8);
      if (m == 0) {
        int R = wv * 64 + i * 16 + quad * 4 + r;
        atomicAdd(&sum[R], s);
        atomicAdd(&ssq[R], q);
      }
    }
  }
#pragma unroll
  for (int i = 0; i < 4; ++i)
#pragma unroll
    for (int j = 0; j < 4; ++j)
#pragma unroll
      for (int r = 0; r < 4; ++r) {
        int R = wv * 64 + i * 16 + quad * 4 + r;
        int hw = hw0 + j * 16 + m;
        if (hw < 784) y[((size_t)b * 256 + R) * 784 + hw] = acc[i][j][r];
      }
}

// ---------------- BN finalize ----------------
__global__ __launch_bounds__(256) void k_bnfinal(const float* __restrict__ gamma,
                                                 const float* __restrict__ beta,
                                                 float* __restrict__ sb) {
  int d = threadIdx.x;
  float mu = sb[SB_SUM + d] * (1.0f / 25088.0f);
  float var = sb[SB_SSQ + d] * (1.0f / 25088.0f) - mu * mu;
  float sc = gamma[d] / sqrtf(var + 1e-5f);
  sb[SB_SCALE + d] = sc;
  sb[SB_SHIFT + d] = beta[d] - mu * sc;
}

// ---------------- BN apply + relu + row-center -> yc fp16 [256][800] -----
__global__ __launch_bounds__(256) void k_bnapply(const float* __restrict__ y,
                                                 const float* __restrict__ sb,
                                                 _Float16* __restrict__ yc) {
  int d = blockIdx.x, b = blockIdx.y, t = threadIdx.x;
  const float* row = y + ((size_t)b * 256 + d) * 784;
  float sc = sb[SB_SCALE + d], sh = sb[SB_SHIFT + d];
  float v[4];
  float s = 0.f;
#pragma unroll
  for (int i = 0; i < 4; ++i) {
    int idx = t + i * 256;
    float u = 0.f;
    if (idx < 784) u = fmaxf(row[idx] * sc + sh, 0.f);
    v[i] = u; s += u;
  }
  __shared__ float red[256];
  red[t] = s; __syncthreads();
  for (int off = 128; off > 0; off >>= 1) {
    if (t < off) red[t] += red[t + off];
    __syncthreads();
  }
  float mean = red[0] * (1.0f / 784.0f);
  _Float16* out = yc + ((size_t)b * 256 + d) * 800;
#pragma unroll
  for (int i = 0; i < 4; ++i) {
    int idx = t + i * 256;
    if (idx < 784) out[idx] = (_Float16)(v[i] - mean);
  }
  if (t < 16) out[784 + t] = (_Float16)0.f;
}

// ---------------- covpool gram: C = yc@yc^T / 784 ----------------
__global__ __launch_bounds__(256) void k_gram(const _Float16* __restrict__ yc,
                                              float* __restrict__ C) {
  int tile = blockIdx.x, b = blockIdx.y;
  int tr = tile >> 2, tc = tile & 3;
  int t = threadIdx.x, wv = t >> 6, lane = t & 63, m = lane & 15, quad = lane >> 4;
  int wr = (wv >> 1) * 32, wc = (wv & 1) * 32;
  __shared__ _Float16 lsA[64 * 40], lsB[64 * 40];
  f32x4 acc[2][2];
#pragma unroll
  for (int i = 0; i < 2; ++i)
#pragma unroll
    for (int j = 0; j < 2; ++j) acc[i][j] = (f32x4){0.f, 0.f, 0.f, 0.f};
  int row = t >> 2, seg = t & 3;
  const _Float16* Ab = yc + ((size_t)b * 256 + tr * 64) * 800;
  const _Float16* Bb = yc + ((size_t)b * 256 + tc * 64) * 800;
  for (int kc = 0; kc < 25; ++kc) {
    int k0 = kc * 32;
    *(uint4*)&lsA[row * 40 + seg * 8] = *(const uint4*)(Ab + (size_t)row * 800 + k0 + seg * 8);
    *(uint4*)&lsB[row * 40 + seg * 8] = *(const uint4*)(Bb + (size_t)row * 800 + k0 + seg * 8);
    __syncthreads();
    f16x8 a0 = *(const f16x8*)&lsA[(wr + m) * 40 + quad * 8];
    f16x8 a1 = *(const f16x8*)&lsA[(wr + 16 + m) * 40 + quad * 8];
    f16x8 b0 = *(const f16x8*)&lsB[(wc + m) * 40 + quad * 8];
    f16x8 b1 = *(const f16x8*)&lsB[(wc + 16 + m) * 40 + quad * 8];
    acc[0][0] = __builtin_amdgcn_mfma_f32_16x16x32_f16(a0, b0, acc[0][0], 0, 0, 0);
    acc[0][1] = __builtin_amdgcn_mfma_f32_16x16x32_f16(a0, b1, acc[0][1], 0, 0, 0);
    acc[1][0] = __builtin_amdgcn_mfma_f32_16x16x32_f16(a1, b0, acc[1][0], 0, 0, 0);
    acc[1][1] = __builtin_amdgcn_mfma_f32_16x16x32_f16(a1, b1, acc[1][1], 0, 0, 0);
    __syncthreads();
  }
  const float inv = 1.0f / 784.0f;
#pragma unroll
  for (int i = 0; i < 2; ++i)
#pragma unroll
    for (int j = 0; j < 2; ++j)
#pragma unroll
      for (int r = 0; r < 4; ++r) {
        int R = tr * 64 + wr + i * 16 + quad * 4 + r;
        int Cc = tc * 64 + wc + j * 16 + m;
        C[((size_t)b * 256 + R) * 256 + Cc] = acc[i][j][r] * inv;
      }
}

// ---------------- diag reductions ----------------
// mode 0: trC from C, then trX = sum(C/trC diag + ij); mode 1: trX from LLT; mode 2: trL
__global__ __launch_bounds__(256) void k_diag(const float* __restrict__ M,
                                              float* __restrict__ sb, int mode) {
  int b = blockIdx.x, t = threadIdx.x;
  __shared__ float red[256];
  float c = M[((size_t)b * 256 + t) * 256 + t];
  if (mode == 0) {
    red[t] = c; __syncthreads();
    for (int off = 128; off > 0; off >>= 1) { if (t < off) red[t] += red[t + off]; __syncthreads(); }
    float trC = red[0]; __syncthreads();
    if (t == 0) sb[SB_TRC + b] = trC;
    float v = c / trC + sb[SB_IJ + t];
    red[t] = v; __syncthreads();
    for (int off = 128; off > 0; off >>= 1) { if (t < off) red[t] += red[t + off]; __syncthreads(); }
    if (t == 0) sb[SB_TRX + b] = red[0];
  } else if (mode == 1) {
    red[t] = c + sb[SB_IJ + t]; __syncthreads();
    for (int off = 128; off > 0; off >>= 1) { if (t < off) red[t] += red[t + off]; __syncthreads(); }
    if (t == 0) sb[SB_TRX + b] = red[0];
  } else {
    red[t] = c; __syncthreads();
    for (int off = 128; off > 0; off >>= 1) { if (t < off) red[t] += red[t + off]; __syncthreads(); }
    if (t == 0) sb[SB_TRL + b] = red[0];
  }
}

// ---------------- prep A and ZY (split bf16); mode0 also writes symC ------
__global__ __launch_bounds__(256) void k_prepAZY(const float* __restrict__ src,
                                                 float* __restrict__ symC,
                                                 u16* __restrict__ Ah, u16* __restrict__ Al,
                                                 u16* __restrict__ ZYh, u16* __restrict__ ZYl,
                                                 const float* __restrict__ sb, int mode) {
  int i = blockIdx.x, b = blockIdx.y, j = threadIdx.x;
  size_t idx = ((size_t)b * 256 + i) * 256 + j;
  float v;
  if (mode == 0) {
    float trC = sb[SB_TRC + b];
    float vij = src[idx] / trC;
    float vji = src[((size_t)b * 256 + j) * 256 + i] / trC;
    symC[idx] = 0.5f * (vij + vji);
    v = vij;
  } else {
    v = src[idx];
  }
  if (i == j) v += sb[SB_IJ + i];
  float A = v / sb[SB_TRX + b];
  u16 h = f2bf(A);
  Ah[idx] = h; Al[idx] = f2bf(A - bf2f(h));
  float zy = 0.5f * ((i == j ? 3.0f : 0.0f) - A);
  h = f2bf(zy);
  ZYh[idx] = h; ZYl[idx] = f2bf(zy - bf2f(h));
}

// ---------------- batched split-bf16 matmul C[i][j] = sum_k A[i][k]*B[j][k]
// (B symmetric => equals A@B). emode: 0 plain->split, 1 ZY=0.5(3I-C)->split,
// 2 C*rsqrt(trX)->split, 3 plain->fp32
struct MMArgs {
  const u16* Ah; const u16* Al; const u16* Bh; const u16* Bl;
  u16* Oh; u16* Ol; float* Of; int emode;
};

__global__ __launch_bounds__(256) void mm_ns(MMArgs g0, MMArgs g1,
                                             const float* __restrict__ sb) {
  MMArgs g = (blockIdx.z == 0) ? g0 : g1;
  int tile = blockIdx.x, b = blockIdx.y;
  int tr = tile >> 2, tc = tile & 3;
  int t = threadIdx.x, wv = t >> 6, lane = t & 63, m = lane & 15, quad = lane >> 4;
  int wr = (wv >> 1) * 32, wc = (wv & 1) * 32;
  __shared__ u16 lsAh[64 * 40], lsAl[64 * 40], lsBh[64 * 40], lsBl[64 * 40];
  f32x4 acc[2][2];
#pragma unroll
  for (int i = 0; i < 2; ++i)
#pragma unroll
    for (int j = 0; j < 2; ++j) acc[i][j] = (f32x4){0.f, 0.f, 0.f, 0.f};
  int row = t >> 2, seg = t & 3;
  size_t aoff = ((size_t)b * 256 + tr * 64) * 256;
  size_t boff = ((size_t)b * 256 + tc * 64) * 256;
  for (int kc = 0; kc < 8; ++kc) {
    int k0 = kc * 32;
    size_t so = (size_t)row * 256 + k0 + seg * 8;
    int lo = row * 40 + seg * 8;
    *(uint4*)&lsAh[lo] = *(const uint4*)(g.Ah + aoff + so);
    *(uint4*)&lsAl[lo] = *(const uint4*)(g.Al + aoff + so);
    *(uint4*)&lsBh[lo] = *(const uint4*)(g.Bh + boff + so);
    *(uint4*)&lsBl[lo] = *(const uint4*)(g.Bl + boff + so);
    __syncthreads();
    bf16x8 ah[2], al[2], bh[2], bl[2];
#pragma unroll
    for (int i = 0; i < 2; ++i) {
      ah[i] = *(const bf16x8*)&lsAh[(wr + i * 16 + m) * 40 + quad * 8];
      al[i] = *(const bf16x8*)&lsAl[(wr + i * 16 + m) * 40 + quad * 8];
      bh[i] = *(const bf16x8*)&lsBh[(wc + i * 16 + m) * 40 + quad * 8];
      bl[i] = *(const bf16x8*)&lsBl[(wc + i * 16 + m) * 40 + quad * 8];
    }
#pragma unroll
    for (int i = 0; i < 2; ++i)
#pragma unroll
      for (int j = 0; j < 2; ++j) {
        acc[i][j] = __builtin_amdgcn_mfma_f32_16x16x32_bf16(ah[i], bh[j], acc[i][j], 0, 0, 0);
        acc[i][j] = __builtin_amdgcn_mfma_f32_16x16x32_bf16(ah[i], bl[j], acc[i][j], 0, 0, 0);
        acc[i][j] = __builtin_amdgcn_mfma_f32_16x16x32_bf16(al[i], bh[j], acc[i][j], 0, 0, 0);
      }
    __syncthreads();
  }
  float scl = 1.0f;
  if (g.emode == 2) scl = 1.0f / sqrtf(sb[SB_TRX + b]);
#pragma unroll
  for (int i = 0; i < 2; ++i)
#pragma unroll
    for (int j = 0; j < 2; ++j)
#pragma unroll
      for (int r = 0; r < 4; ++r) {
        int R = tr * 64 + wr + i * 16 + quad * 4 + r;
        int Cc = tc * 64 + wc + j * 16 + m;
        float v = acc[i][j][r];
        if (g.emode == 1) v = 0.5f * ((R == Cc ? 3.0f : 0.0f) - v);
        else if (g.emode == 2) v = v * scl;
        size_t oidx = ((size_t)b * 256 + R) * 256 + Cc;
        if (g.emode == 3) {
          g.Of[oidx] = v;
        } else {
          u16 h = f2bf(v);
          g.Oh[oidx] = h;
          g.Ol[oidx] = f2bf(v - bf2f(h));
        }
      }
}

// ---------------- SICE elementwise update (with symmetrize) ----------------
__global__ __launch_bounds__(256) void k_sice(const float* __restrict__ LLT,
                                              const float* __restrict__ P,
                                              const float* __restrict__ symC,
                                              float* __restrict__ out, float dec) {
  int i = blockIdx.x, b = blockIdx.y, j = threadIdx.x;
  size_t idx = ((size_t)b * 256 + i) * 256 + j;
  size_t tdx = ((size_t)b * 256 + j) * 256 + i;
  float L = LLT[idx], Lt = LLT[tdx];
  float g = symC[idx] - P[idx], gt = symC[tdx] - P[tdx];
  float f = fmaxf(fmaxf(L, 0.f) - dec * (g + 0.07f), 0.f) -
            fmaxf(fmaxf(-L, 0.f) - dec * (-g + 0.07f), 0.f);
  float ft = fmaxf(fmaxf(Lt, 0.f) - dec * (gt + 0.07f), 0.f) -
             fmaxf(fmaxf(-Lt, 0.f) - dec * (-gt + 0.07f), 0.f);
  out[idx] = 0.5f * (f + ft);
}

// ---------------- triu-vec output ----------------
__global__ __launch_bounds__(256) void k_out(const float* __restrict__ LLT,
                                             const float* __restrict__ sb,
                                             float* __restrict__ out) {
  int i = blockIdx.x, b = blockIdx.y, j = threadIdx.x;
  if (j < i) return;
  float inv = 1.0f / sqrtf(sb[SB_TRL + b]);
  int tl = i * 256 - (i * (i - 1)) / 2 + (j - i);
  out[(size_t)b * 32896 + tl] = LLT[((size_t)b * 256 + i) * 256 + j] * inv;
}

extern "C" void kernel_launch(void* const* d_in, const int* in_sizes, int n_in,
                              void* d_out, int out_size, void* d_ws, size_t ws_size,
                              hipStream_t stream) {
  const float* x = (const float*)d_in[0];
  const float* w = (const float*)d_in[1];
  const float* gamma = (const float*)d_in[2];
  const float* beta = (const float*)d_in[3];
  const float* jitter = (const float*)d_in[4];
  char* ws = (char*)d_ws;

  _Float16* w_half = (_Float16*)(ws + 0);                      // 1,048,576
  float* sb = (float*)(ws + 1048576);                          // 8 KB
  float* y = (float*)(ws + 2097152);                           // 25,690,112
  _Float16* yc = (_Float16*)(ws + 27787264);                   // 13,107,200
  _Float16* xt = (_Float16*)(ws + 40894464);                   // 102,760,448
  // NS-phase overlay inside xt region (xt dead after k_conv):
  char* ov = ws + 40894464;
  float* Craw = (float*)(ov + 0);
  float* symC = (float*)(ov + 8388608);
  float* LLTa = (float*)(ov + 16777216);
  float* P = (float*)(ov + 25165824);
  float* LLTb = (float*)(ov + 33554432);
  u16* bf[12];
  for (int i = 0; i < 12; ++i) bf[i] = (u16*)(ov + 41943040 + (size_t)i * 4194304);

  k_prep<<<2048, 256, 0, stream>>>(w, jitter, w_half, sb);
  k_xt<<<dim3(13, 32, 32), 256, 0, stream>>>(x, xt);
  k_conv<<<dim3(13, 32), 256, 0, stream>>>(w_half, xt, y, sb);
  k_bnfinal<<<1, 256, 0, stream>>>(gamma, beta, sb);
  k_bnapply<<<dim3(256, 32), 256, 0, stream>>>(y, sb, yc);
  k_gram<<<dim3(16, 32), 256, 0, stream>>>(yc, Craw);

  auto run_ns = [&](const float* src, int mode, float* Pout) {
    k_diag<<<32, 256, 0, stream>>>(src, sb, mode == 0 ? 0 : 1);
    k_prepAZY<<<dim3(256, 32), 256, 0, stream>>>(src, symC, bf[0], bf[1], bf[2], bf[3], sb, mode);
    u16 *Ah = bf[0], *Al = bf[1], *ZYh = bf[2], *ZYl = bf[3];
    u16 *Yh = bf[4], *Yl = bf[5], *Z2h = bf[6], *Z2l = bf[7];
    u16 *Th = bf[8], *Tl = bf[9], *zzh = bf[10], *zzl = bf[11];
    // Y = A @ ZY ; Z = ZY
    MMArgs m1{Ah, Al, ZYh, ZYl, Yh, Yl, nullptr, 0};
    mm_ns<<<dim3(16, 32, 1), 256, 0, stream>>>(m1, m1, sb);
    u16 *Ych = Yh, *Ycl = Yl, *Yah = Ah, *Yal = Al;  // A bufs dead -> Y alt
    u16 *Zch = ZYh, *Zcl = ZYl, *Zah = Z2h, *Zal = Z2l;
    for (int it = 0; it < 5; ++it) {
      MMArgs mt{Zch, Zcl, Ych, Ycl, Th, Tl, nullptr, 1};  // T = 0.5(3I - Z@Y)
      mm_ns<<<dim3(16, 32, 1), 256, 0, stream>>>(mt, mt, sb);
      MMArgs my{Ych, Ycl, Th, Tl, Yah, Yal, nullptr, 0};  // Y' = Y@T
      MMArgs mz{Th, Tl, Zch, Zcl, Zah, Zal, nullptr, 0};  // Z' = T@Z
      mm_ns<<<dim3(16, 32, 2), 256, 0, stream>>>(my, mz, sb);
      std::swap(Ych, Yah); std::swap(Ycl, Yal);
      std::swap(Zch, Zah); std::swap(Zcl, Zal);
    }
    MMArgs mt6{Zch, Zcl, Ych, Ycl, Th, Tl, nullptr, 1};
    mm_ns<<<dim3(16, 32, 1), 256, 0, stream>>>(mt6, mt6, sb);
    MMArgs mz7{Th, Tl, Zch, Zcl, zzh, zzl, nullptr, 2};   // zz = T@Z * rsqrt(trX)
    mm_ns<<<dim3(16, 32, 1), 256, 0, stream>>>(mz7, mz7, sb);
    MMArgs mzz{zzh, zzl, zzh, zzl, nullptr, nullptr, Pout, 3};  // P = zz@zz
    mm_ns<<<dim3(16, 32, 1), 256, 0, stream>>>(mzz, mzz, sb);
  };

  run_ns(Craw, 0, LLTa);  // LLT init = zz@zz (also writes symC)
  run_ns(LLTa, 1, P);     // SICE i=0
  k_sice<<<dim3(256, 32), 256, 0, stream>>>(LLTa, P, symC, LLTb, 5.0f);
  run_ns(LLTb, 1, P);     // SICE i=1
  k_sice<<<dim3(256, 32), 256, 0, stream>>>(LLTb, P, symC, LLTa, 2.5f);
  // SICE i=2: dec=0 -> provable no-op (relu(x)-relu(-x)=x; symmetrize idempotent)

  k_diag<<<32, 256, 0, stream>>>(LLTa, sb, 2);
  k_out<<<dim3(256, 32), 256, 0, stream>>>(LLTa, sb, (float*)d_out);
}

// Round 2
// 1018.797 us; speedup vs baseline: 1.1824x; 1.1824x over previous
//
#include <hip/hip_runtime.h>
#include <utility>

// SICE head for MI355X (gfx950) — round 2.
// R2 changes vs R1: reg-prefetch double-buffer in all GEMM K-loops; 1-D grids
// with batch in low 5 bits (XCD = b%8 locality, NS working set ~3MB/XCD L2);
// k_conv hw-tile 64->32 (800 WGs); trace reductions fused into producer
// epilogues (k_diag eliminated); bnfinal fused into bnapply; y stored fp16;
// k_sice tile-based coalesced with LDS transpose.

typedef unsigned short u16;
typedef __attribute__((ext_vector_type(8))) __bf16 bf16x8;
typedef __attribute__((ext_vector_type(8))) _Float16 f16x8;
typedef __attribute__((ext_vector_type(4))) float f32x4;

#define DEV __device__ __forceinline__

DEV u16 f2bf(float f) {
  unsigned x = __float_as_uint(f);
  x += 0x7fffu + ((x >> 16) & 1u);
  return (u16)(x >> 16);
}
DEV float bf2f(u16 h) { return __uint_as_float(((unsigned)h) << 16); }

// sb float-index layout
#define SB_SUM   0
#define SB_SSQ   256
#define SB_IJ    512
#define SB_TRC   768
#define SB_TR2   800
#define SB_TR3   832
#define SB_TRL   864
#define SB_DEN   896
#define SB_IJSUM 928

// ---------------- prep: w -> fp16, init sb ----------------
__global__ __launch_bounds__(256) void k_prep(const float* __restrict__ w,
                                              const float* __restrict__ jitter,
                                              _Float16* __restrict__ w_half,
                                              float* __restrict__ sb) {
  int gid = blockIdx.x * 256 + threadIdx.x;
  if (gid < 256 * 2048) w_half[gid] = (_Float16)w[gid];
  if (blockIdx.x == 0) {
    int t = threadIdx.x;
    sb[SB_SUM + t] = 0.f;
    sb[SB_SSQ + t] = 0.f;
    float ij = 1e-10f + 1e-9f * jitter[t];
    sb[SB_IJ + t] = ij;
    if (t < 160) sb[SB_TRC + t] = 0.f;  // TRC,TR2,TR3,TRL,DEN all zeroed
    __shared__ float red[256];
    red[t] = ij; __syncthreads();
    for (int off = 128; off > 0; off >>= 1) {
      if (t < off) red[t] += red[t + off];
      __syncthreads();
    }
    if (t == 0) sb[SB_IJSUM] = red[0];
  }
}

// ---------------- x[b,c,hw] f32 -> xt[b,hw,c] f16 ----------------
__global__ __launch_bounds__(256) void k_xt(const float* __restrict__ x,
                                            _Float16* __restrict__ xt) {
  int ht = blockIdx.x;  // 0..12 (hw tiles of 64)
  int ct = blockIdx.y;  // 0..31 (c tiles of 64)
  int b = blockIdx.z;
  int t = threadIdx.x;
  __shared__ _Float16 ls[64 * 68];
  int hw0 = ht * 64, c0 = ct * 64;
  const float* xb = x + ((size_t)b * 2048 + c0) * 784;
#pragma unroll
  for (int it = 0; it < 4; ++it) {
    int cc = (t >> 4) + it * 16;
    int s = t & 15;
    int hw = hw0 + s * 4;
    float4 v = make_float4(0.f, 0.f, 0.f, 0.f);
    if (hw < 784) v = *(const float4*)(xb + (size_t)cc * 784 + hw);
    _Float16* d = &ls[cc * 68 + s * 4];
    d[0] = (_Float16)v.x; d[1] = (_Float16)v.y;
    d[2] = (_Float16)v.z; d[3] = (_Float16)v.w;
  }
  __syncthreads();
#pragma unroll
  for (int it = 0; it < 2; ++it) {
    int idx = t + it * 256;
    int hwr = idx >> 3, s8 = idx & 7;
    if (hw0 + hwr < 784) {
      union { _Float16 h[8]; uint4 v; } pk;
#pragma unroll
      for (int cc = 0; cc < 8; ++cc) pk.h[cc] = ls[(s8 * 8 + cc) * 68 + hwr];
      *(uint4*)(xt + ((size_t)b * 784 + hw0 + hwr) * 2048 + c0 + s8 * 8) = pk.v;
    }
  }
}

// ---------------- conv: y[b,d,hw] = w@x (fp16 out) + BN stats ----------------
// grid 800 = 25 hw-tiles(32) x 32 b; b = x&31 for XCD locality of y.
__global__ __launch_bounds__(256) void k_conv(const _Float16* __restrict__ w_half,
                                              const _Float16* __restrict__ xt,
                                              _Float16* __restrict__ y,
                                              float* __restrict__ sb) {
  int xb = blockIdx.x;
  int ht = xb >> 5, b = xb & 31;
  int t = threadIdx.x;
  int wv = t >> 6, lane = t & 63, m = lane & 15, quad = lane >> 4;
  __shared__ _Float16 lsA[256 * 40];
  __shared__ _Float16 lsB[32 * 40];
  int hw0 = ht * 32;
  f32x4 acc[4][2];
#pragma unroll
  for (int i = 0; i < 4; ++i)
#pragma unroll
    for (int j = 0; j < 2; ++j) acc[i][j] = (f32x4){0.f, 0.f, 0.f, 0.f};
  int rowA = t >> 2, segA = t & 3;
  const _Float16* wp = w_half + (size_t)rowA * 2048 + segA * 8;
  bool doB = (t < 128);
  int hw = hw0 + rowA;  // rowA 0..31 for t<128
  const _Float16* xp = xt + ((size_t)b * 784 + hw) * 2048 + segA * 8;
  uint4 ra0, ra1, ra2, ra3, rb;
  ra0 = *(const uint4*)(wp);
  ra1 = *(const uint4*)(wp + 64 * 2048);
  ra2 = *(const uint4*)(wp + 128 * 2048);
  ra3 = *(const uint4*)(wp + 192 * 2048);
  rb = (uint4){0u, 0u, 0u, 0u};
  if (doB && hw < 784) rb = *(const uint4*)(xp);
  for (int kc = 0; kc < 64; ++kc) {
    int lo = rowA * 40 + segA * 8;
    *(uint4*)&lsA[lo] = ra0;
    *(uint4*)&lsA[lo + 64 * 40] = ra1;
    *(uint4*)&lsA[lo + 128 * 40] = ra2;
    *(uint4*)&lsA[lo + 192 * 40] = ra3;
    if (doB) *(uint4*)&lsB[lo] = rb;
    __syncthreads();
    if (kc < 63) {
      int k0 = (kc + 1) * 32;
      ra0 = *(const uint4*)(wp + k0);
      ra1 = *(const uint4*)(wp + 64 * 2048 + k0);
      ra2 = *(const uint4*)(wp + 128 * 2048 + k0);
      ra3 = *(const uint4*)(wp + 192 * 2048 + k0);
      rb = (uint4){0u, 0u, 0u, 0u};
      if (doB && hw < 784) rb = *(const uint4*)(xp + k0);
    }
    f16x8 af[4], bfg[2];
#pragma unroll
    for (int i = 0; i < 4; ++i)
      af[i] = *(const f16x8*)&lsA[(wv * 64 + i * 16 + m) * 40 + quad * 8];
#pragma unroll
    for (int j = 0; j < 2; ++j)
      bfg[j] = *(const f16x8*)&lsB[(j * 16 + m) * 40 + quad * 8];
#pragma unroll
    for (int i = 0; i < 4; ++i)
#pragma unroll
      for (int j = 0; j < 2; ++j)
        acc[i][j] = __builtin_amdgcn_mfma_f32_16x16x32_f16(af[i], bfg[j], acc[i][j], 0, 0, 0);
    __syncthreads();
  }
  float* sum = sb + SB_SUM;
  float* ssq = sb + SB_SSQ;
#pragma unroll
  for (int i = 0; i < 4; ++i) {
#pragma unroll
    for (int r = 0; r < 4; ++r) {
      float s = 0.f, q = 0.f;
#pragma unroll
      for (int j = 0; j < 2; ++j) {
        float v = acc[i][j][r];
        s += v; q += v * v;
      }
      s += __shfl_xor(s, 1); s += __shfl_xor(s, 2);
      s += __shfl_xor(s, 4); s += __shfl_xor(s, 8);
      q += __shfl_xor(q, 1); q += __shfl_xor(q, 2);
      q += __shfl_xor(q, 4); q += __shfl_xor(q, 8);
      if (m == 0) {
        int R = wv * 64 + i * 16 + quad * 4 + r;
        atomicAdd(&sum[R], s);
        atomicAdd(&ssq[R], q);
      }
    }
  }
#pragma unroll
  for (int i = 0; i < 4; ++i)
#pragma unroll
    for (int j = 0; j < 2; ++j)
#pragma unroll
      for (int r = 0; r < 4; ++r) {
        int R = wv * 64 + i * 16 + quad * 4 + r;
        int hwc = hw0 + j * 16 + m;
        if (hwc < 784) y[((size_t)b * 256 + R) * 784 + hwc] = (_Float16)acc[i][j][r];
      }
}

// ---------------- BN finalize+apply + relu + row-center -> yc fp16 --------
__global__ __launch_bounds__(256) void k_bnapply(const _Float16* __restrict__ y,
                                                 const float* __restrict__ gamma,
                                                 const float* __restrict__ beta,
                                                 const float* __restrict__ sb,
                                                 _Float16* __restrict__ yc) {
  int xb = blockIdx.x;
  int d = xb >> 5, b = xb & 31, t = threadIdx.x;
  float mu = sb[SB_SUM + d] * (1.0f / 25088.0f);
  float var = sb[SB_SSQ + d] * (1.0f / 25088.0f) - mu * mu;
  float sc = gamma[d] / sqrtf(var + 1e-5f);
  float sh = beta[d] - mu * sc;
  const _Float16* row = y + ((size_t)b * 256 + d) * 784;
  float v[4];
  float s = 0.f;
#pragma unroll
  for (int i = 0; i < 4; ++i) {
    int idx = t + i * 256;
    float u = 0.f;
    if (idx < 784) u = fmaxf((float)row[idx] * sc + sh, 0.f);
    v[i] = u; s += u;
  }
  __shared__ float red[256];
  red[t] = s; __syncthreads();
  for (int off = 128; off > 0; off >>= 1) {
    if (t < off) red[t] += red[t + off];
    __syncthreads();
  }
  float mean = red[0] * (1.0f / 784.0f);
  _Float16* out = yc + ((size_t)b * 256 + d) * 800;
#pragma unroll
  for (int i = 0; i < 4; ++i) {
    int idx = t + i * 256;
    if (idx < 784) out[idx] = (_Float16)(v[i] - mean);
  }
  if (t < 16) out[784 + t] = (_Float16)0.f;
}

// ---------------- covpool gram: C = yc@yc^T / 784, + trace(C) atomics -----
__global__ __launch_bounds__(256) void k_gram(const _Float16* __restrict__ yc,
                                              float* __restrict__ C,
                                              float* __restrict__ sb) {
  int xb = blockIdx.x;
  int tile = xb >> 5, b = xb & 31;
  int tr = tile >> 2, tc = tile & 3;
  int t = threadIdx.x, wv = t >> 6, lane = t & 63, m = lane & 15, quad = lane >> 4;
  int wr = (wv >> 1) * 32, wc = (wv & 1) * 32;
  __shared__ _Float16 lsA[64 * 40], lsB[64 * 40];
  f32x4 acc[2][2];
#pragma unroll
  for (int i = 0; i < 2; ++i)
#pragma unroll
    for (int j = 0; j < 2; ++j) acc[i][j] = (f32x4){0.f, 0.f, 0.f, 0.f};
  int row = t >> 2, seg = t & 3;
  const _Float16* Ap = yc + ((size_t)b * 256 + tr * 64 + row) * 800 + seg * 8;
  const _Float16* Bp = yc + ((size_t)b * 256 + tc * 64 + row) * 800 + seg * 8;
  uint4 rA = *(const uint4*)(Ap);
  uint4 rB = *(const uint4*)(Bp);
  for (int kc = 0; kc < 25; ++kc) {
    int lo = row * 40 + seg * 8;
    *(uint4*)&lsA[lo] = rA;
    *(uint4*)&lsB[lo] = rB;
    __syncthreads();
    if (kc < 24) {
      int k0 = (kc + 1) * 32;
      rA = *(const uint4*)(Ap + k0);
      rB = *(const uint4*)(Bp + k0);
    }
    f16x8 a0 = *(const f16x8*)&lsA[(wr + m) * 40 + quad * 8];
    f16x8 a1 = *(const f16x8*)&lsA[(wr + 16 + m) * 40 + quad * 8];
    f16x8 b0 = *(const f16x8*)&lsB[(wc + m) * 40 + quad * 8];
    f16x8 b1 = *(const f16x8*)&lsB[(wc + 16 + m) * 40 + quad * 8];
    acc[0][0] = __builtin_amdgcn_mfma_f32_16x16x32_f16(a0, b0, acc[0][0], 0, 0, 0);
    acc[0][1] = __builtin_amdgcn_mfma_f32_16x16x32_f16(a0, b1, acc[0][1], 0, 0, 0);
    acc[1][0] = __builtin_amdgcn_mfma_f32_16x16x32_f16(a1, b0, acc[1][0], 0, 0, 0);
    acc[1][1] = __builtin_amdgcn_mfma_f32_16x16x32_f16(a1, b1, acc[1][1], 0, 0, 0);
    __syncthreads();
  }
  const float inv = 1.0f / 784.0f;
#pragma unroll
  for (int i = 0; i < 2; ++i)
#pragma unroll
    for (int j = 0; j < 2; ++j)
#pragma unroll
      for (int r = 0; r < 4; ++r) {
        int R = tr * 64 + wr + i * 16 + quad * 4 + r;
        int Cc = tc * 64 + wc + j * 16 + m;
        float v = acc[i][j][r] * inv;
        C[((size_t)b * 256 + R) * 256 + Cc] = v;
        if (R == Cc) atomicAdd(&sb[SB_TRC + b], v);
      }
}

// ---------------- prep A and ZY (split bf16); mode0 also writes symC ------
__global__ __launch_bounds__(256) void k_prepAZY(const float* __restrict__ src,
                                                 float* __restrict__ symC,
                                                 u16* __restrict__ Ah, u16* __restrict__ Al,
                                                 u16* __restrict__ ZYh, u16* __restrict__ ZYl,
                                                 float* __restrict__ sb, int slot, int mode) {
  int xb = blockIdx.x;
  int i = xb >> 5, b = xb & 31, j = threadIdx.x;
  float trv = (mode == 0) ? 1.0f : sb[slot + b];
  float denom = trv + sb[SB_IJSUM];
  if (i == 0 && j == 0) sb[SB_DEN + b] = denom;
  size_t idx = ((size_t)b * 256 + i) * 256 + j;
  float v;
  if (mode == 0) {
    float trC = sb[SB_TRC + b];
    float vij = src[idx] / trC;
    float vji = src[((size_t)b * 256 + j) * 256 + i] / trC;
    symC[idx] = 0.5f * (vij + vji);
    v = vij;
  } else {
    v = src[idx];
  }
  if (i == j) v += sb[SB_IJ + i];
  float A = v / denom;
  u16 h = f2bf(A);
  Ah[idx] = h; Al[idx] = f2bf(A - bf2f(h));
  float zy = 0.5f * ((i == j ? 3.0f : 0.0f) - A);
  h = f2bf(zy);
  ZYh[idx] = h; ZYl[idx] = f2bf(zy - bf2f(h));
}

// ---------------- batched split-bf16 matmul C[i][j] = sum_k A[i][k]*B[j][k]
// emode: 0 plain->split, 1 ZY=0.5(3I-C)->split, 2 C*rsqrt(den)->split, 3 ->f32
struct MMArgs {
  const u16* Ah; const u16* Al; const u16* Bh; const u16* Bl;
  u16* Oh; u16* Ol; float* Of; float* tr; int emode;
};

__global__ __launch_bounds__(256) void mm_ns(MMArgs g0, MMArgs g1,
                                             const float* __restrict__ sb) {
  int xb = blockIdx.x;
  int b = xb & 31;
  int rest = xb >> 5;
  MMArgs g = (rest < 16) ? g0 : g1;
  int tile = rest & 15;
  int tr = tile >> 2, tc = tile & 3;
  int t = threadIdx.x, wv = t >> 6, lane = t & 63, m = lane & 15, quad = lane >> 4;
  int wr = (wv >> 1) * 32, wc = (wv & 1) * 32;
  __shared__ u16 lsAh[64 * 40], lsAl[64 * 40], lsBh[64 * 40], lsBl[64 * 40];
  f32x4 acc[2][2];
#pragma unroll
  for (int i = 0; i < 2; ++i)
#pragma unroll
    for (int j = 0; j < 2; ++j) acc[i][j] = (f32x4){0.f, 0.f, 0.f, 0.f};
  int row = t >> 2, seg = t & 3;
  size_t aoff = ((size_t)b * 256 + tr * 64 + row) * 256 + seg * 8;
  size_t boff = ((size_t)b * 256 + tc * 64 + row) * 256 + seg * 8;
  uint4 rAh = *(const uint4*)(g.Ah + aoff);
  uint4 rAl = *(const uint4*)(g.Al + aoff);
  uint4 rBh = *(const uint4*)(g.Bh + boff);
  uint4 rBl = *(const uint4*)(g.Bl + boff);
  for (int kc = 0; kc < 8; ++kc) {
    int lo = row * 40 + seg * 8;
    *(uint4*)&lsAh[lo] = rAh;
    *(uint4*)&lsAl[lo] = rAl;
    *(uint4*)&lsBh[lo] = rBh;
    *(uint4*)&lsBl[lo] = rBl;
    __syncthreads();
    if (kc < 7) {
      int k0 = (kc + 1) * 32;
      rAh = *(const uint4*)(g.Ah + aoff + k0);
      rAl = *(const uint4*)(g.Al + aoff + k0);
      rBh = *(const uint4*)(g.Bh + boff + k0);
      rBl = *(const uint4*)(g.Bl + boff + k0);
    }
    bf16x8 ah[2], al[2], bh[2], bl[2];
#pragma unroll
    for (int i = 0; i < 2; ++i) {
      ah[i] = *(const bf16x8*)&lsAh[(wr + i * 16 + m) * 40 + quad * 8];
      al[i] = *(const bf16x8*)&lsAl[(wr + i * 16 + m) * 40 + quad * 8];
      bh[i] = *(const bf16x8*)&lsBh[(wc + i * 16 + m) * 40 + quad * 8];
      bl[i] = *(const bf16x8*)&lsBl[(wc + i * 16 + m) * 40 + quad * 8];
    }
#pragma unroll
    for (int i = 0; i < 2; ++i)
#pragma unroll
      for (int j = 0; j < 2; ++j) {
        acc[i][j] = __builtin_amdgcn_mfma_f32_16x16x32_bf16(ah[i], bh[j], acc[i][j], 0, 0, 0);
        acc[i][j] = __builtin_amdgcn_mfma_f32_16x16x32_bf16(ah[i], bl[j], acc[i][j], 0, 0, 0);
        acc[i][j] = __builtin_amdgcn_mfma_f32_16x16x32_bf16(al[i], bh[j], acc[i][j], 0, 0, 0);
      }
    __syncthreads();
  }
  float scl = 1.0f;
  if (g.emode == 2) scl = 1.0f / sqrtf(sb[SB_DEN + b]);
#pragma unroll
  for (int i = 0; i < 2; ++i)
#pragma unroll
    for (int j = 0; j < 2; ++j)
#pragma unroll
      for (int r = 0; r < 4; ++r) {
        int R = tr * 64 + wr + i * 16 + quad * 4 + r;
        int Cc = tc * 64 + wc + j * 16 + m;
        float v = acc[i][j][r];
        if (g.emode == 1) v = 0.5f * ((R == Cc ? 3.0f : 0.0f) - v);
        else if (g.emode == 2) v = v * scl;
        size_t oidx = ((size_t)b * 256 + R) * 256 + Cc;
        if (g.emode == 3) {
          g.Of[oidx] = v;
          if (R == Cc && g.tr) atomicAdd(g.tr + b, v);
        } else {
          u16 h = f2bf(v);
          g.Oh[oidx] = h;
          g.Ol[oidx] = f2bf(v - bf2f(h));
        }
      }
}

// ---------------- SICE elementwise update, tile-symmetric ----------------
__global__ __launch_bounds__(256) void k_sice(const float* __restrict__ LLT,
                                              const float* __restrict__ P,
                                              const float* __restrict__ symC,
                                              float* __restrict__ out,
                                              float* __restrict__ sb, int slot,
                                              float dec) {
  int xb = blockIdx.x;
  int b = xb & 31, p = xb >> 5;
  const int TRt[10] = {0, 0, 0, 0, 1, 1, 1, 2, 2, 3};
  const int TCt[10] = {0, 1, 2, 3, 1, 2, 3, 2, 3, 3};
  int tr = TRt[p], tc = TCt[p];
  __shared__ float ft[64][65];
  __shared__ float ot[64][65];
  int t = threadIdx.x;
  size_t base = (size_t)b * 65536;
  // phase A: f over mirror tile (tc,tr)
#pragma unroll 4
  for (int it = 0; it < 16; ++it) {
    int idx = it * 256 + t;
    int r = idx >> 6, c = idx & 63;
    size_t o = base + (size_t)(tc * 64 + r) * 256 + tr * 64 + c;
    float L = LLT[o];
    float g = symC[o] - P[o];
    float f = fmaxf(fmaxf(L, 0.f) - dec * (g + 0.07f), 0.f) -
              fmaxf(fmaxf(-L, 0.f) - dec * (-g + 0.07f), 0.f);
    ft[r][c] = f;
  }
  __syncthreads();
  float tsum = 0.f;
#pragma unroll 4
  for (int it = 0; it < 16; ++it) {
    int idx = it * 256 + t;
    int r = idx >> 6, c = idx & 63;
    size_t o = base + (size_t)(tr * 64 + r) * 256 + tc * 64 + c;
    float L = LLT[o];
    float g = symC[o] - P[o];
    float f = fmaxf(fmaxf(L, 0.f) - dec * (g + 0.07f), 0.f) -
              fmaxf(fmaxf(-L, 0.f) - dec * (-g + 0.07f), 0.f);
    float val = 0.5f * (f + ft[c][r]);
    out[o] = val;
    ot[r][c] = val;
    if (tr == tc && r == c) tsum += val;
  }
  if (tr == tc) {
    if (tsum != 0.f) atomicAdd(&sb[slot + b], tsum);
  } else {
    __syncthreads();
#pragma unroll 4
    for (int it = 0; it < 16; ++it) {
      int idx = it * 256 + t;
      int r = idx >> 6, c = idx & 63;
      size_t o = base + (size_t)(tc * 64 + r) * 256 + tr * 64 + c;
      out[o] = ot[c][r];
    }
  }
}

// ---------------- triu-vec output ----------------
__global__ __launch_bounds__(256) void k_out(const float* __restrict__ LLT,
                                             const float* __restrict__ sb,
                                             float* __restrict__ out) {
  int xb = blockIdx.x;
  int i = xb >> 5, b = xb & 31, j = threadIdx.x;
  if (j < i) return;
  float inv = 1.0f / sqrtf(sb[SB_TRL + b]);
  int tl = i * 256 - (i * (i - 1)) / 2 + (j - i);
  out[(size_t)b * 32896 + tl] = LLT[((size_t)b * 256 + i) * 256 + j] * inv;
}

extern "C" void kernel_launch(void* const* d_in, const int* in_sizes, int n_in,
                              void* d_out, int out_size, void* d_ws, size_t ws_size,
                              hipStream_t stream) {
  const float* x = (const float*)d_in[0];
  const float* w = (const float*)d_in[1];
  const float* gamma = (const float*)d_in[2];
  const float* beta = (const float*)d_in[3];
  const float* jitter = (const float*)d_in[4];
  char* ws = (char*)d_ws;

  _Float16* w_half = (_Float16*)(ws + 0);            // 1 MB
  float* sb = (float*)(ws + (1 << 20));              // 4 KB
  _Float16* y = (_Float16*)(ws + (2 << 20));         // 12.85 MB
  _Float16* yc = (_Float16*)(ws + (16 << 20));       // 13.1 MB
  _Float16* xt = (_Float16*)(ws + (32 << 20));       // 102.8 MB
  // NS-phase overlay inside xt region (xt dead after k_conv):
  char* ov = ws + (32 << 20);
  float* Craw = (float*)(ov + 0);
  float* symC = (float*)(ov + 8388608);
  float* LLTa = (float*)(ov + 16777216);
  float* P = (float*)(ov + 25165824);
  float* LLTb = (float*)(ov + 33554432);
  u16* bf[12];
  for (int i = 0; i < 12; ++i) bf[i] = (u16*)(ov + 41943040 + (size_t)i * 4194304);

  k_prep<<<2048, 256, 0, stream>>>(w, jitter, w_half, sb);
  k_xt<<<dim3(13, 32, 32), 256, 0, stream>>>(x, xt);
  k_conv<<<800, 256, 0, stream>>>(w_half, xt, y, sb);
  k_bnapply<<<8192, 256, 0, stream>>>(y, gamma, beta, sb, yc);
  k_gram<<<512, 256, 0, stream>>>(yc, Craw, sb);

  auto run_ns = [&](const float* src, int mode, int slot_in, float* Pout,
                    float* tr_out) {
    k_prepAZY<<<8192, 256, 0, stream>>>(src, symC, bf[0], bf[1], bf[2], bf[3], sb, slot_in, mode);
    u16 *Ah = bf[0], *Al = bf[1], *ZYh = bf[2], *ZYl = bf[3];
    u16 *Yh = bf[4], *Yl = bf[5], *Z2h = bf[6], *Z2l = bf[7];
    u16 *Th = bf[8], *Tl = bf[9], *zzh = bf[10], *zzl = bf[11];
    // Y = A @ ZY ; Z = ZY
    MMArgs m1{Ah, Al, ZYh, ZYl, Yh, Yl, nullptr, nullptr, 0};
    mm_ns<<<512, 256, 0, stream>>>(m1, m1, sb);
    u16 *Ych = Yh, *Ycl = Yl, *Yah = Ah, *Yal = Al;
    u16 *Zch = ZYh, *Zcl = ZYl, *Zah = Z2h, *Zal = Z2l;
    for (int it = 0; it < 5; ++it) {
      MMArgs mt{Zch, Zcl, Ych, Ycl, Th, Tl, nullptr, nullptr, 1};
      mm_ns<<<512, 256, 0, stream>>>(mt, mt, sb);
      MMArgs my{Ych, Ycl, Th, Tl, Yah, Yal, nullptr, nullptr, 0};
      MMArgs mz{Th, Tl, Zch, Zcl, Zah, Zal, nullptr, nullptr, 0};
      mm_ns<<<1024, 256, 0, stream>>>(my, mz, sb);
      std::swap(Ych, Yah); std::swap(Ycl, Yal);
      std::swap(Zch, Zah); std::swap(Zcl, Zal);
    }
    MMArgs mt6{Zch, Zcl, Ych, Ycl, Th, Tl, nullptr, nullptr, 1};
    mm_ns<<<512, 256, 0, stream>>>(mt6, mt6, sb);
    MMArgs mz7{Th, Tl, Zch, Zcl, zzh, zzl, nullptr, nullptr, 2};
    mm_ns<<<512, 256, 0, stream>>>(mz7, mz7, sb);
    MMArgs mzz{zzh, zzl, zzh, zzl, nullptr, nullptr, Pout, tr_out, 3};
    mm_ns<<<512, 256, 0, stream>>>(mzz, mzz, sb);
  };

  run_ns(Craw, 0, 0, LLTa, sb + SB_TR2);   // LLT init (trace -> TR2)
  run_ns(LLTa, 1, SB_TR2, P, nullptr);     // SICE i=0
  k_sice<<<320, 256, 0, stream>>>(LLTa, P, symC, LLTb, sb, SB_TR3, 5.0f);
  run_ns(LLTb, 1, SB_TR3, P, nullptr);     // SICE i=1
  k_sice<<<320, 256, 0, stream>>>(LLTb, P, symC, LLTa, sb, SB_TRL, 2.5f);
  // SICE i=2: dec=0 -> provable no-op

  k_out<<<8192, 256, 0, stream>>>(LLTa, sb, (float*)d_out);
}